// Round 1
// baseline (99.007 us; speedup 1.0000x reference)
//
#include <hip/hip_runtime.h>

// Problem constants (reference: B=64, IN=1024, OUT=1024, D=32)
#define NB 64
#define NIN 1024
#define NOUT 1024

// ---------------------------------------------------------------------------
// K1: per-batch presence bitmask over hidden_rank values (0..32), plus
// masked x transposed into [j4][b] float4 layout for coalesced GEMM loads.
// Grid: 64 blocks (one per batch) x 256 threads (one per j4 group of 4 j).
// ---------------------------------------------------------------------------
__global__ __launch_bounds__(256) void k_prep(
    const float* __restrict__ x, const int* __restrict__ hr,
    const int* __restrict__ rl, float4* __restrict__ xmT4,
    unsigned long long* __restrict__ present)
{
    const int b   = blockIdx.x;
    const int tid = threadIdx.x;

    __shared__ unsigned int mlo, mhi;
    if (tid == 0) { mlo = 0u; mhi = 0u; }
    __syncthreads();

    // Each thread scans 4 hidden_rank values (coalesced int4).
    int4 h = ((const int4*)hr)[b * 256 + tid];
    unsigned int lo = 0u, hi = 0u;
    int vv[4] = { h.x, h.y, h.z, h.w };
#pragma unroll
    for (int e = 0; e < 4; ++e) {
        int v = vv[e] & 63;          // values are 0..32; &63 keeps shift defined
        if (v < 32) lo |= 1u << v;
        else        hi |= 1u << (v - 32);
    }
    atomicOr(&mlo, lo);
    atomicOr(&mhi, hi);
    __syncthreads();

    const unsigned long long pres =
        ((unsigned long long)mhi << 32) | (unsigned long long)mlo;
    if (tid == 0) present[b] = pres;

    // xm[b,j] = x[b,j] * [rl[j] != 0 && rl[j] present in hidden_rank[b,:]]
    int4   rlv = ((const int4*)rl)[tid];
    float4 xv  = ((const float4*)x)[b * 256 + tid];
    float4 o;
    o.x = (rlv.x != 0 && ((pres >> (rlv.x & 63)) & 1ull)) ? xv.x : 0.0f;
    o.y = (rlv.y != 0 && ((pres >> (rlv.y & 63)) & 1ull)) ? xv.y : 0.0f;
    o.z = (rlv.z != 0 && ((pres >> (rlv.z & 63)) & 1ull)) ? xv.z : 0.0f;
    o.w = (rlv.w != 0 && ((pres >> (rlv.w & 63)) & 1ull)) ? xv.w : 0.0f;
    xmT4[tid * 64 + b] = o;   // [j4][b] layout: lane=b coalesced in GEMM
}

// ---------------------------------------------------------------------------
// K2: masked GEMM  y[b,k] = sum_j W[k,j] * [rl[j] <= rh[k]] * xm[b,j]
// Grid: (64 k-blocks) x NJC j-chunks. Block = 256 threads = 4 waves.
// Wave w owns k = kb*16 + w*4 + {0..3}; lane = batch. All W/rl/rh accesses
// are wave-uniform -> scalar loads; mask select is scalar -> ~1 v_fmac/MAC.
// ---------------------------------------------------------------------------
__global__ __launch_bounds__(256) void k_gemm(
    const float4* __restrict__ xmT4, const float* __restrict__ W,
    const int* __restrict__ rl, const int* __restrict__ rh,
    float* __restrict__ partial, int njc)
{
    const int bi   = blockIdx.x;
    const int kb   = bi & 63;      // 64 k-blocks of 16 k each
    const int jc   = bi >> 6;      // j-chunk id (0..njc-1)
    const int lane = threadIdx.x & 63;
    const int wv   = __builtin_amdgcn_readfirstlane((int)(threadIdx.x >> 6));
    const int k0   = kb * 16 + wv * 4;

    const int jchunk4 = 256 / njc;        // j4 groups per chunk
    const int j4base  = jc * jchunk4;

    const int rh0 = rh[k0 + 0];
    const int rh1 = rh[k0 + 1];
    const int rh2 = rh[k0 + 2];
    const int rh3 = rh[k0 + 3];

    const float4* W0 = (const float4*)(W + (size_t)(k0 + 0) * NIN);
    const float4* W1 = (const float4*)(W + (size_t)(k0 + 1) * NIN);
    const float4* W2 = (const float4*)(W + (size_t)(k0 + 2) * NIN);
    const float4* W3 = (const float4*)(W + (size_t)(k0 + 3) * NIN);
    const int4*   RL = (const int4*)rl;

    float a0 = 0.0f, a1 = 0.0f, a2 = 0.0f, a3 = 0.0f;

    for (int t = 0; t < jchunk4; ++t) {
        const int j4 = j4base + t;
        float4 xv  = xmT4[j4 * 64 + lane];   // coalesced vector load
        int4   rl4 = RL[j4];                  // uniform -> s_load
        float4 w0 = W0[j4], w1 = W1[j4], w2 = W2[j4], w3 = W3[j4]; // uniform

        // element x
        a0 = fmaf((rl4.x <= rh0) ? w0.x : 0.0f, xv.x, a0);
        a1 = fmaf((rl4.x <= rh1) ? w1.x : 0.0f, xv.x, a1);
        a2 = fmaf((rl4.x <= rh2) ? w2.x : 0.0f, xv.x, a2);
        a3 = fmaf((rl4.x <= rh3) ? w3.x : 0.0f, xv.x, a3);
        // element y
        a0 = fmaf((rl4.y <= rh0) ? w0.y : 0.0f, xv.y, a0);
        a1 = fmaf((rl4.y <= rh1) ? w1.y : 0.0f, xv.y, a1);
        a2 = fmaf((rl4.y <= rh2) ? w2.y : 0.0f, xv.y, a2);
        a3 = fmaf((rl4.y <= rh3) ? w3.y : 0.0f, xv.y, a3);
        // element z
        a0 = fmaf((rl4.z <= rh0) ? w0.z : 0.0f, xv.z, a0);
        a1 = fmaf((rl4.z <= rh1) ? w1.z : 0.0f, xv.z, a1);
        a2 = fmaf((rl4.z <= rh2) ? w2.z : 0.0f, xv.z, a2);
        a3 = fmaf((rl4.z <= rh3) ? w3.z : 0.0f, xv.z, a3);
        // element w
        a0 = fmaf((rl4.w <= rh0) ? w0.w : 0.0f, xv.w, a0);
        a1 = fmaf((rl4.w <= rh1) ? w1.w : 0.0f, xv.w, a1);
        a2 = fmaf((rl4.w <= rh2) ? w2.w : 0.0f, xv.w, a2);
        a3 = fmaf((rl4.w <= rh3) ? w3.w : 0.0f, xv.w, a3);
    }

    // partial[jc][k][b], coalesced stores (lane = b)
    float* p = partial + (size_t)jc * (NOUT * NB);
    p[(k0 + 0) * 64 + lane] = a0;
    p[(k0 + 1) * 64 + lane] = a1;
    p[(k0 + 2) * 64 + lane] = a2;
    p[(k0 + 3) * 64 + lane] = a3;
}

// ---------------------------------------------------------------------------
// K3: reduce NJC partials; out[b,k] = om*scale[k]*y + om*bias[k]
// Grid: 256 blocks x 256 threads = 65536 outputs, lanes -> k (coalesced out).
// ---------------------------------------------------------------------------
__global__ __launch_bounds__(256) void k_epi(
    const float* __restrict__ partial,
    const unsigned long long* __restrict__ present,
    const int* __restrict__ rh, const float* __restrict__ sb,
    const float* __restrict__ bb, float* __restrict__ out, int njc)
{
    const int gid = blockIdx.x * 256 + threadIdx.x;   // 0..65535
    const int b = gid >> 10;
    const int k = gid & 1023;

    float y = 0.0f;
    for (int jc = 0; jc < njc; ++jc)
        y += partial[(size_t)jc * (NOUT * NB) + k * 64 + b];

    const unsigned long long pres = present[b];
    const int rhk = rh[k] & 63;
    const float om = (float)((pres >> rhk) & 1ull);
    out[gid] = om * sb[k] * y + om * bb[k];
}

// ---------------------------------------------------------------------------
extern "C" void kernel_launch(void* const* d_in, const int* in_sizes, int n_in,
                              void* d_out, int out_size, void* d_ws, size_t ws_size,
                              hipStream_t stream)
{
    (void)in_sizes; (void)n_in; (void)out_size;
    const float* x  = (const float*)d_in[0];
    // d_in[1]=mask, d_in[2]=pre_mask unused by the math
    const int*   hr = (const int*)d_in[3];
    const int*   rl = (const int*)d_in[4];
    const int*   rh = (const int*)d_in[5];
    const float* W  = (const float*)d_in[6];
    // d_in[7]=cscale_w, d_in[9]=cbias_w multiplied by zeros in the reference
    const float* sb = (const float*)d_in[8];
    const float* bb = (const float*)d_in[10];
    float* out = (float*)d_out;

    // Workspace layout: partial[NJC][1024][64] | xmT4[256][64] | present[64]
    const size_t base = (size_t)NOUT * NB * sizeof(float);   // 256 KiB
    int njc;
    if      (ws_size >= 17 * base + 4096) njc = 16;
    else if (ws_size >=  5 * base + 4096) njc = 4;
    else                                  njc = 1;

    float*              partial = (float*)d_ws;
    float4*             xmT4    = (float4*)((char*)d_ws + (size_t)njc * base);
    unsigned long long* present =
        (unsigned long long*)((char*)d_ws + (size_t)(njc + 1) * base);

    k_prep<<<dim3(64), dim3(256), 0, stream>>>(x, hr, rl, xmT4, present);
    k_gemm<<<dim3(64 * njc), dim3(256), 0, stream>>>(xmT4, W, rl, rh, partial, njc);
    k_epi<<<dim3(256), dim3(256), 0, stream>>>(partial, present, rh, sb, bb, out, njc);
}